// Round 1
// baseline (725.344 us; speedup 1.0000x reference)
//
#include <hip/hip_runtime.h>

// One workgroup (512 thr) per group n (1024 groups of 16ch x 64x64).
// Phases: stage x->LDS bf16 | row/col means | gating (16x16 matmuls) |
// 3x3 conv via mfma_f32_16x16x32_bf16 (x3 -> bf16, spilled into d_out even rows) |
// x1 stats (sum/sq/min/max) | finalize groupnorm+softmax constants |
// Z-sums (exp) | final: s = sigmoid(sum_c q3*e3 + q1*e1), out = x_fp32 * s.

typedef short bf16x8 __attribute__((ext_vector_type(8)));
typedef float f32x4 __attribute__((ext_vector_type(4)));

__device__ __forceinline__ unsigned short f2bf(float f) {
    union { float f; unsigned int u; } v; v.f = f;
    unsigned int u = v.u;
    u += 0x7fffu + ((u >> 16) & 1u);          // RNE
    return (unsigned short)(u >> 16);
}
__device__ __forceinline__ float bf2f(unsigned short h) {
    union { unsigned int u; float f; } v; v.u = ((unsigned int)h) << 16;
    return v.f;
}
__device__ __forceinline__ float sigm(float v) { return 1.0f / (1.0f + __expf(-v)); }

// LDS x layout: [h1][blk][w1][8ch] bf16; blk = c>>3. 16B blocks rotate bank-quads with w1.
#define XIDX(h1,w1,c) ((((h1)*2 + ((c)>>3))*66 + (w1))*8 + ((c)&7))

__global__ __launch_bounds__(512) void ema_fused(
    const float* __restrict__ x,
    const float* __restrict__ w1, const float* __restrict__ b1,
    const float* __restrict__ wh, const float* __restrict__ bh,
    const float* __restrict__ ww, const float* __restrict__ bw,
    const float* __restrict__ w3, const float* __restrict__ b3,
    const float* __restrict__ gamma, const float* __restrict__ beta,
    float* __restrict__ out)
{
    const int n   = blockIdx.x;
    const int tid = threadIdx.x;
    const int lane = tid & 63;
    const int wv   = tid >> 6;       // wave 0..7
    const int qd   = lane >> 4;      // quad 0..3
    const int col  = lane & 15;

    const float* xg = x + (size_t)n * 65536;
    unsigned int* ob = (unsigned int*)out + (size_t)n * 65536;  // all d_out access via uint (no TBAA games)

    __shared__ unsigned short sX[69696];                 // 139392 B padded bf16 x
    __shared__ float sG[2048];                           // means -> y2 -> gates: ah[c*64+h], aw[1024+c*64+w]
    __shared__ float sRedA[128], sRedB[128], sRedC[128], sRedD[128];
    __shared__ float sS1[16], sSQ[16], sMn[16], sMx[16], sM3[16], sS3[16];
    __shared__ float sA[16], sB1[16], sQ1[16], sQ3[16];
    __shared__ float sScal[2];

    // ---- Phase 1: zero-pad + stage x -> LDS bf16 ----
    for (int i = tid; i < 34848; i += 512) ((unsigned int*)sX)[i] = 0u;
    __syncthreads();
    for (int e = tid; e < 32768; e += 512) {
        int c2 = e & 7, w = (e >> 3) & 63, r = e >> 9;
        float v0 = xg[(2*c2)*4096 + r*64 + w];
        float v1 = xg[(2*c2+1)*4096 + r*64 + w];
        unsigned int pk = (unsigned int)f2bf(v0) | ((unsigned int)f2bf(v1) << 16);
        ((unsigned int*)sX)[XIDX(r+1, w+1, 2*c2) >> 1] = pk;
    }
    __syncthreads();

    // ---- Phase 2: row means (x_h) and col means (x_w) ----
    if (tid < 256) {
        int half = tid & 1;
        int idx  = tid >> 1;          // 0..127
        int isCol = idx >> 6;         // 0: mean over w at r=idx ; 1: mean over h at w=idx-64
        int rc = idx & 63;
        float acc[8] = {0,0,0,0,0,0,0,0};
        for (int t = 0; t < 64; ++t) {
            int hh = isCol ? (t + 1) : (rc + 1);
            int wwi = isCol ? (rc + 1) : (t + 1);
            const bf16x8 v = *(const bf16x8*)&sX[XIDX(hh, wwi, half*8)];
            #pragma unroll
            for (int j = 0; j < 8; ++j) acc[j] += bf2f((unsigned short)v[j]);
        }
        #pragma unroll
        for (int j = 0; j < 8; ++j)
            sG[isCol*1024 + (half*8+j)*64 + rc] = acc[j] * (1.0f/64.0f);
    }
    __syncthreads();

    // ---- Phase 3a: y2[o][q] = silu(W1 @ [xh;xw] + b1), q in [0,128) ----
    {
        float yv[4];
        #pragma unroll
        for (int j = 0; j < 4; ++j) {
            int tsk = tid + j*512;             // 0..2047
            int o = tsk & 15, q = tsk >> 4;
            float acc = b1[o];
            #pragma unroll
            for (int i = 0; i < 16; ++i)
                acc += w1[o*16 + i] * sG[((q>>6)<<10) + i*64 + (q & 63)];
            yv[j] = acc * sigm(acc);
        }
        __syncthreads();
        #pragma unroll
        for (int j = 0; j < 4; ++j) {
            int tsk = tid + j*512;
            int o = tsk & 15, q = tsk >> 4;
            sG[o*128 + q] = yv[j];
        }
    }
    __syncthreads();
    // ---- Phase 3b: a_h = sigmoid(Wh@y_h+bh), a_w = sigmoid(Ww@y_w+bw) ----
    {
        float av[4];
        #pragma unroll
        for (int j = 0; j < 4; ++j) {
            int tsk = tid + j*512;
            int kind = tsk >> 10;              // 0: ah, 1: aw
            int o = tsk & 15, pos = (tsk >> 4) & 63;
            const float* wm = kind ? ww : wh;
            float acc = kind ? bw[o] : bh[o];
            #pragma unroll
            for (int i = 0; i < 16; ++i)
                acc += wm[o*16 + i] * sG[i*128 + kind*64 + pos];
            av[j] = sigm(acc);
        }
        __syncthreads();
        #pragma unroll
        for (int j = 0; j < 4; ++j) {
            int tsk = tid + j*512;
            int kind = tsk >> 10, o = tsk & 15, pos = (tsk >> 4) & 63;
            sG[kind*1024 + o*64 + pos] = av[j];
        }
    }
    __syncthreads();

    // ---- Phase 4: 3x3 conv via MFMA, x3 = silu(conv+b3) -> bf16 into ob even rows; max/sum stats ----
    {
        // A fragments (weights), lane: m=out=col, k=qd*8+j -> tap t=2*mm+(qd>>1), in-ch i=(qd&1)*8+j
        bf16x8 afr[5];
        int offs[5];
        #pragma unroll
        for (int mm = 0; mm < 5; ++mm) {
            int t = 2*mm + (qd >> 1);
            #pragma unroll
            for (int j = 0; j < 8; ++j) {
                int i = ((qd & 1) << 3) + j;
                float v = (t <= 8) ? w3[(col*16 + i)*9 + t] : 0.0f;
                afr[mm][j] = (short)f2bf(v);
            }
            int tb = (t > 8) ? 8 : t;
            int dy = tb/3 - 1, dx = tb - (tb/3)*3 - 1;
            offs[mm] = dy*1056 + dx*8;          // h1 coeff 1056, w1 coeff 8 (ushort units)
        }
        float b3v[4];
        #pragma unroll
        for (int r = 0; r < 4; ++r) b3v[r] = b3[qd*4 + r];

        float tmax[4] = {-1e30f,-1e30f,-1e30f,-1e30f};
        float tsum[4] = {0.f,0.f,0.f,0.f};

        for (int k = 0; k < 32; ++k) {
            int tile = wv*32 + k;               // 0..255
            int h = tile >> 2, wq = tile & 3;
            int base = XIDX(h+1, wq*16 + col + 1, (qd & 1)*8);
            f32x4 acc = {0.f, 0.f, 0.f, 0.f};
            #pragma unroll
            for (int mm = 0; mm < 5; ++mm) {
                const bf16x8 bfr = *(const bf16x8*)&sX[base + offs[mm]];
                acc = __builtin_amdgcn_mfma_f32_16x16x32_bf16(afr[mm], bfr, acc, 0, 0, 0);
            }
            int p = h*64 + wq*16 + col;
            float xv[4];
            #pragma unroll
            for (int r = 0; r < 4; ++r) {
                float v = acc[r] + b3v[r];
                float sv = v * sigm(v);
                xv[r] = sv;
                tmax[r] = fmaxf(tmax[r], sv);
                tsum[r] += sv;
            }
            unsigned int u0 = (unsigned int)f2bf(xv[0]) | ((unsigned int)f2bf(xv[1]) << 16);
            unsigned int u1 = (unsigned int)f2bf(xv[2]) | ((unsigned int)f2bf(xv[3]) << 16);
            ob[(4*qd)*4096 + p]     = u0;       // channels 4qd,4qd+1
            ob[(4*qd + 2)*4096 + p] = u1;       // channels 4qd+2,4qd+3
        }
        #pragma unroll
        for (int m = 1; m < 16; m <<= 1) {
            #pragma unroll
            for (int r = 0; r < 4; ++r) {
                tmax[r] = fmaxf(tmax[r], __shfl_xor(tmax[r], m, 64));
                tsum[r] += __shfl_xor(tsum[r], m, 64);
            }
        }
        if (col == 0) {
            #pragma unroll
            for (int r = 0; r < 4; ++r) {
                sRedA[wv*16 + qd*4 + r] = tmax[r];
                sRedB[wv*16 + qd*4 + r] = tsum[r];
            }
        }
    }
    __syncthreads();
    if (tid < 16) {
        float mx = -1e30f, sm = 0.f;
        for (int v2 = 0; v2 < 8; ++v2) { mx = fmaxf(mx, sRedA[v2*16 + tid]); sm += sRedB[v2*16 + tid]; }
        sM3[tid] = mx; sS3[tid] = sm;
    }
    __syncthreads();

    // ---- Phase 5: x1 = x*ah*aw stats: per-ch sum/sq/min/max ----
    {
        int half = tid & 1;
        int wq4  = (tid >> 1) & 3;
        int r    = tid >> 3;               // 0..63
        float ah8[8];
        #pragma unroll
        for (int j = 0; j < 8; ++j) ah8[j] = sG[(half*8+j)*64 + r];
        float s1[8], q1[8], mn[8], mx[8];
        #pragma unroll
        for (int j = 0; j < 8; ++j) { s1[j]=0.f; q1[j]=0.f; mn[j]=1e30f; mx[j]=-1e30f; }
        for (int wi = 0; wi < 16; ++wi) {
            int w = wq4*16 + wi;
            const bf16x8 v = *(const bf16x8*)&sX[XIDX(r+1, w+1, half*8)];
            #pragma unroll
            for (int j = 0; j < 8; ++j) {
                float aw = sG[1024 + (half*8+j)*64 + w];
                float x1 = bf2f((unsigned short)v[j]) * ah8[j] * aw;
                s1[j] += x1; q1[j] += x1*x1;
                mn[j] = fminf(mn[j], x1); mx[j] = fmaxf(mx[j], x1);
            }
        }
        #pragma unroll
        for (int m = 2; m < 64; m <<= 1) {
            #pragma unroll
            for (int j = 0; j < 8; ++j) {
                s1[j] += __shfl_xor(s1[j], m, 64);
                q1[j] += __shfl_xor(q1[j], m, 64);
                mn[j] = fminf(mn[j], __shfl_xor(mn[j], m, 64));
                mx[j] = fmaxf(mx[j], __shfl_xor(mx[j], m, 64));
            }
        }
        if ((lane >> 1) == 0) {            // lanes 0 (ch0-7) and 1 (ch8-15)
            #pragma unroll
            for (int j = 0; j < 8; ++j) {
                int c = half*8 + j;
                sRedA[wv*16 + c] = s1[j];
                sRedB[wv*16 + c] = q1[j];
                sRedC[wv*16 + c] = mn[j];
                sRedD[wv*16 + c] = mx[j];
            }
        }
    }
    __syncthreads();
    if (tid < 16) {
        float s=0.f, q=0.f, mn=1e30f, mx=-1e30f;
        for (int v2 = 0; v2 < 8; ++v2) {
            s += sRedA[v2*16+tid]; q += sRedB[v2*16+tid];
            mn = fminf(mn, sRedC[v2*16+tid]); mx = fmaxf(mx, sRedD[v2*16+tid]);
        }
        sS1[tid]=s; sSQ[tid]=q; sMn[tid]=mn; sMx[tid]=mx;
    }
    __syncthreads();
    if (tid == 0) {
        float S=0.f, Q=0.f;
        for (int c = 0; c < 16; ++c) { S += sS1[c]; Q += sSQ[c]; }
        float mu = S * (1.0f/65536.0f);
        float var = Q * (1.0f/65536.0f) - mu*mu;
        sScal[0] = mu; sScal[1] = rsqrtf(var + 1e-5f);
    }
    __syncthreads();
    if (tid < 16) {
        float mu = sScal[0], rstd = sScal[1];
        float a  = gamma[tid] * rstd;
        float bb = beta[tid] - mu * a;                 // x1n = a*x1 + bb
        float m1 = (a >= 0.f) ? (a*sMx[tid] + bb) : (a*sMn[tid] + bb);
        sA[tid]  = a;
        sB1[tid] = bb - m1;                            // shifted logit = a*x1 + (bb-m1)
        sMn[tid] = a * (sS1[tid] * (1.0f/4096.0f)) + bb;   // v1
        sMx[tid] = sS3[tid] * (1.0f/4096.0f);              // v3
    }
    __syncthreads();

    // ---- Phase 7: Z1/Z3 exp-sums ----
    {
        float z1[16], z3[16];
        #pragma unroll
        for (int c = 0; c < 16; ++c) { z1[c]=0.f; z3[c]=0.f; }
        for (int pp = 0; pp < 8; ++pp) {
            int p = pp*512 + tid;
            int h = p >> 6, w = p & 63;
            const bf16x8 v0 = *(const bf16x8*)&sX[XIDX(h+1, w+1, 0)];
            const bf16x8 v1 = *(const bf16x8*)&sX[XIDX(h+1, w+1, 8)];
            unsigned int xq[8];
            #pragma unroll
            for (int c2 = 0; c2 < 8; ++c2) xq[c2] = ob[(2*c2)*4096 + p];
            #pragma unroll
            for (int c = 0; c < 16; ++c) {
                float xv = bf2f((unsigned short)((c < 8) ? v0[c] : v1[c-8]));
                float g = sG[c*64 + h] * sG[1024 + c*64 + w];
                z1[c] += __expf(xv*g*sA[c] + sB1[c]);
                unsigned short ub = (unsigned short)((c & 1) ? (xq[c>>1] >> 16) : (xq[c>>1] & 0xffffu));
                z3[c] += __expf(bf2f(ub) - sM3[c]);
            }
        }
        #pragma unroll
        for (int m = 1; m < 64; m <<= 1) {
            #pragma unroll
            for (int c = 0; c < 16; ++c) {
                z1[c] += __shfl_xor(z1[c], m, 64);
                z3[c] += __shfl_xor(z3[c], m, 64);
            }
        }
        if (lane == 0) {
            #pragma unroll
            for (int c = 0; c < 16; ++c) { sRedA[wv*16 + c] = z1[c]; sRedB[wv*16 + c] = z3[c]; }
        }
    }
    __syncthreads();
    if (tid < 16) {
        float a1=0.f, a3=0.f;
        for (int v2 = 0; v2 < 8; ++v2) { a1 += sRedA[v2*16+tid]; a3 += sRedB[v2*16+tid]; }
        sQ1[tid] = sMx[tid] / a1;      // v3 / Z1  (weights e1)
        sQ3[tid] = sMn[tid] / a3;      // v1 / Z3  (weights e3)
    }
    __syncthreads();

    // ---- Phase 8: s = sigmoid(sum_c q3*e3 + q1*e1); out = x_fp32 * s ----
    for (int pp = 0; pp < 8; ++pp) {
        int p = pp*512 + tid;
        int h = p >> 6, w = p & 63;
        const bf16x8 v0 = *(const bf16x8*)&sX[XIDX(h+1, w+1, 0)];
        const bf16x8 v1 = *(const bf16x8*)&sX[XIDX(h+1, w+1, 8)];
        unsigned int xq[8];
        #pragma unroll
        for (int c2 = 0; c2 < 8; ++c2) xq[c2] = ob[(2*c2)*4096 + p];
        float xf[16];
        #pragma unroll
        for (int c = 0; c < 16; ++c) xf[c] = xg[c*4096 + p];
        float z = 0.f;
        #pragma unroll
        for (int c = 0; c < 16; ++c) {
            float xv = bf2f((unsigned short)((c < 8) ? v0[c] : v1[c-8]));
            float g = sG[c*64 + h] * sG[1024 + c*64 + w];
            float e1 = __expf(xv*g*sA[c] + sB1[c]);
            unsigned short ub = (unsigned short)((c & 1) ? (xq[c>>1] >> 16) : (xq[c>>1] & 0xffffu));
            float e3 = __expf(bf2f(ub) - sM3[c]);
            z += sQ3[c]*e3 + sQ1[c]*e1;
        }
        float s = 1.0f / (1.0f + __expf(-z));
        #pragma unroll
        for (int c = 0; c < 16; ++c)
            ob[c*4096 + p] = __float_as_uint(xf[c] * s);   // only clobbers own p's x3 slots (already read)
    }
}

extern "C" void kernel_launch(void* const* d_in, const int* in_sizes, int n_in,
                              void* d_out, int out_size, void* d_ws, size_t ws_size,
                              hipStream_t stream) {
    const float* x     = (const float*)d_in[0];
    const float* w1    = (const float*)d_in[1];
    const float* b1    = (const float*)d_in[2];
    const float* wh    = (const float*)d_in[3];
    const float* bh    = (const float*)d_in[4];
    const float* ww    = (const float*)d_in[5];
    const float* bw    = (const float*)d_in[6];
    const float* w3    = (const float*)d_in[7];
    const float* b3    = (const float*)d_in[8];
    const float* gamma = (const float*)d_in[9];
    const float* beta  = (const float*)d_in[10];
    hipLaunchKernelGGL(ema_fused, dim3(1024), dim3(512), 0, stream,
                       x, w1, b1, wh, bh, ww, bw, w3, b3, gamma, beta, (float*)d_out);
}